// Round 7
// baseline (387.945 us; speedup 1.0000x reference)
//
#include <hip/hip_runtime.h>
#include <math.h>

#define NSEG 126

__device__ __forceinline__ unsigned bitrev8(unsigned v) { return __brev(v) >> 24; }

// ---------------------------------------------------------------------------
// K interleaved register-resident 256-point DIF FFTs per wave (proven R5 core).
// FFT k: element e = i*64 + lane in x[k][i]. On exit x[k][i] = X[bitrev8(e)].
// ---------------------------------------------------------------------------
template <int K>
__device__ __forceinline__ void fftK(float2 x[][4], int lane) {
    const float PI = 3.14159265358979323846f;
    {   // stage M=256
        float s, c;
        __sincosf(-PI * (float)lane * (1.0f / 128.0f), &s, &c);
        #pragma unroll
        for (int k = 0; k < K; k++) {
            float2 u, t, d;
            u = x[k][0]; t = x[k][2];
            x[k][0] = make_float2(u.x + t.x, u.y + t.y);
            d = make_float2(u.x - t.x, u.y - t.y);
            x[k][2] = make_float2(d.x * c - d.y * s, d.x * s + d.y * c);
            u = x[k][1]; t = x[k][3];
            x[k][1] = make_float2(u.x + t.x, u.y + t.y);
            d = make_float2(u.x - t.x, u.y - t.y);
            x[k][3] = make_float2(d.x * s + d.y * c, -d.x * c + d.y * s); // * (s,-c)
        }
    }
    {   // stage M=128
        float s, c;
        __sincosf(-PI * (float)lane * (1.0f / 64.0f), &s, &c);
        #pragma unroll
        for (int k = 0; k < K; k++) {
            float2 u, t, d;
            u = x[k][0]; t = x[k][1];
            x[k][0] = make_float2(u.x + t.x, u.y + t.y);
            d = make_float2(u.x - t.x, u.y - t.y);
            x[k][1] = make_float2(d.x * c - d.y * s, d.x * s + d.y * c);
            u = x[k][2]; t = x[k][3];
            x[k][2] = make_float2(u.x + t.x, u.y + t.y);
            d = make_float2(u.x - t.x, u.y - t.y);
            x[k][3] = make_float2(d.x * c - d.y * s, d.x * s + d.y * c);
        }
    }
    #pragma unroll
    for (int hbit = 5; hbit >= 0; hbit--) {   // stages M=64..2, cross-lane
        int h = 1 << hbit;
        int j = lane & (h - 1);
        float s, c;
        __sincosf(-PI * (float)j / (float)h, &s, &c);
        bool up = (lane & h) != 0;
        #pragma unroll
        for (int k = 0; k < K; k++) {
            #pragma unroll
            for (int i = 0; i < 4; i++) {
                float px = __shfl_xor(x[k][i].x, h);
                float py = __shfl_xor(x[k][i].y, h);
                if (up) {
                    float dx = px - x[k][i].x, dy = py - x[k][i].y;
                    x[k][i] = make_float2(dx * c - dy * s, dx * s + dy * c);
                } else {
                    x[k][i] = make_float2(x[k][i].x + px, x[k][i].y + py);
                }
            }
        }
    }
}

// ---------------------------------------------------------------------------
// prep: keep half-plane (c>128 || (c==128 && r>128)); bucket j = 255-c;
// pack (bitrev(r), bitrev(256-r), seg).
// ---------------------------------------------------------------------------
__global__ void prep_zero(int* counts) {
    int i = threadIdx.x;                          // 128 threads
    counts[i] = 0;
}

__device__ __forceinline__ bool keep_point(int r, int c) {
    return (c > 128) || (c == 128 && r > 128);
}

__global__ void prep_hist(const int* __restrict__ rr, const int* __restrict__ cc,
                          int n, int* counts) {
    int i = blockIdx.x * 256 + threadIdx.x;
    if (i < n) {
        int c = cc[i], r = rr[i];
        if (keep_point(r, c)) atomicAdd(&counts[255 - c], 1);
    }
}

__global__ void prep_scan(const int* __restrict__ counts, int* starts, int* cursor) {
    int lane = threadIdx.x;                      // 64 threads, 2 counts each
    int2 c = reinterpret_cast<const int2*>(counts)[lane];
    int lsum = c.x + c.y;
    int pre = lsum;
    #pragma unroll
    for (int off = 1; off < 64; off <<= 1) {
        int v = __shfl_up(pre, off);
        if (lane >= off) pre += v;
    }
    int excl = pre - lsum;
    int2 outv = make_int2(excl, excl + c.x);
    reinterpret_cast<int2*>(starts)[lane] = outv;
    reinterpret_cast<int2*>(cursor)[lane] = outv;
    if (lane == 63) starts[128] = excl + c.x + c.y;
}

__global__ void prep_scatter(const int* __restrict__ rr, const int* __restrict__ cc,
                             const int* __restrict__ seg, int n, int* cursor,
                             int* b_pack) {
    int i = blockIdx.x * 256 + threadIdx.x;
    if (i < n) {
        int c = cc[i], r = rr[i];
        if (keep_point(r, c)) {
            int j = 255 - c;
            int pos = atomicAdd(&cursor[j], 1);
            int pr = (int)bitrev8((unsigned)r);
            int pm = (int)bitrev8((unsigned)(256 - r) & 255);
            b_pack[pos] = pr | (pm << 8) | (seg[i] << 16);
        }
    }
}

// ---------------------------------------------------------------------------
// Row-pass: packed z = in + i*tgt; 512 thr = 8 waves x 4 rows = 32 rows/block.
// G stored ROW-major natural-v: each FFT's output is un-bitreversed on the fly
// into two float4 stores per reg-pair (full 2 KB row span per wave, L2-merged).
// No LDS, no barriers.
// ---------------------------------------------------------------------------
__global__ __launch_bounds__(512, 2) void rowfft_kernel(
    const float* __restrict__ inp, const float* __restrict__ tgt,
    float2* __restrict__ G, int pair_base)
{
    int tid    = threadIdx.x;
    int wv     = tid >> 6;
    int lane   = tid & 63;
    int plocal = blockIdx.x >> 3;
    int rowgrp = blockIdx.x & 7;                  // 8 blocks/pair, 32 rows each
    int row0   = (rowgrp << 5) + (wv << 2);
    int b6     = (int)(__brev((unsigned)lane) >> 26);   // bitrev6(lane)

    size_t ibase = (((size_t)(pair_base + plocal)) << 16) + ((size_t)row0 << 8);
    const float* s1 = inp + ibase;
    const float* s2 = tgt + ibase;

    float2 x[4][4];
    #pragma unroll
    for (int k = 0; k < 4; k++)
        #pragma unroll
        for (int i = 0; i < 4; i++) {
            int e = (k << 8) + (i << 6) + lane;
            x[k][i] = make_float2(s1[e], s2[e]);
        }

    fftK<4>(x, lane);

    // natural position of elem e=i*64+lane is 4*b6 + br2(i); br2 = {0,2,1,3}
    // -> (x[0],x[2]) contiguous at 4*b6, (x[1],x[3]) at 4*b6+2
    float2* dst = G + (((size_t)plocal) << 16) + ((size_t)row0 << 8) + (b6 << 2);
    #pragma unroll
    for (int k = 0; k < 4; k++) {
        float4* d4 = reinterpret_cast<float4*>(dst + (k << 8));
        d4[0] = make_float4(x[k][0].x, x[k][0].y, x[k][2].x, x[k][2].y);
        d4[1] = make_float4(x[k][1].x, x[k][1].y, x[k][3].x, x[k][3].y);
    }
}

// ---------------------------------------------------------------------------
// Column-pass + gather. 512 thr = 8 waves; block = 16 buckets (32 columns:
// lo band jb+1..jb+16, hi band 240-jb..255-jb, both contiguous in natural-v).
// Tile-stage bands in LDS, wave w FFTs its 4 columns (2 buckets), two-phase
// gather from per-wave LDS slot aliased over the tile. Block partials ->
// scratch row (no global atomics).
// ---------------------------------------------------------------------------
__global__ __launch_bounds__(512, 2) void colfft_gather_kernel(
    const float2* __restrict__ G, const int* __restrict__ starts,
    const int* __restrict__ b_pack, float* __restrict__ partials, int row_base)
{
    __shared__ float2 tile[256 * 33];            // 67584 B (F slots alias this)
    __shared__ float accl[NSEG * 3];
    int tid    = threadIdx.x;
    int wv     = tid >> 6;
    int lane   = tid & 63;
    int plocal = blockIdx.x >> 3;
    int bq     = blockIdx.x & 7;
    int jb     = bq << 4;                        // buckets [jb, jb+16)

    for (int i = tid; i < NSEG * 3; i += 512) accl[i] = 0.f;

    const float2* Gp = G + (((size_t)plocal) << 16);
    int lo_c = jb + 1, hi_c = 240 - jb;

    #pragma unroll
    for (int k = 0; k < 8; k++) {                // lo band: 16 cols x 256 x
        int idx = tid + (k << 9);
        int c16 = idx & 15, xx = idx >> 4;
        tile[xx * 33 + c16] = Gp[xx * 256 + lo_c + c16];
    }
    #pragma unroll
    for (int k = 0; k < 8; k++) {                // hi band
        int idx = tid + (k << 9);
        int c16 = idx & 15, xx = idx >> 4;
        tile[xx * 33 + 16 + c16] = Gp[xx * 256 + hi_c + c16];
    }
    __syncthreads();

    // wave w: buckets jb+2w, jb+2w+1; tile cols {2w, 31-2w, 2w+1, 30-2w}
    int colk[4];
    colk[0] = 2 * wv;      colk[1] = 31 - 2 * wv;
    colk[2] = 2 * wv + 1;  colk[3] = 30 - 2 * wv;

    float2 x[4][4];
    #pragma unroll
    for (int k = 0; k < 4; k++)
        #pragma unroll
        for (int i = 0; i < 4; i++)
            x[k][i] = tile[((i << 6) + lane) * 33 + colk[k]];
    __syncthreads();                             // tile consumed -> slots free

    fftK<4>(x, lane);

    float2* slot = tile + (wv << 9);             // 4 KiB per wave
    #pragma unroll
    for (int kb = 0; kb < 2; kb++) {
        #pragma unroll
        for (int i = 0; i < 4; i++) {
            slot[(i << 6) + lane]       = x[2 * kb + 0][i];   // F_lo
            slot[256 + (i << 6) + lane] = x[2 * kb + 1][i];   // F_hi
        }
        int j = jb + 2 * wv + kb;
        int s0 = starts[j], s1 = starts[j + 1];
        int e  = s0 + lane;
        int pk = (e < s1) ? b_pack[e] : 0;
        while (e < s1) {
            int e2  = e + 64;
            int pk2 = (e2 < s1) ? b_pack[e2] : 0;
            float2 a = slot[256 + (pk & 255)];        // Fp(r, c)
            float2 m = slot[(pk >> 8) & 255];         // Fp(-r, -c)
            int sg = pk >> 16;
            float f1x = a.x + m.x, f1y = a.y - m.y;   // 2*F1
            float dx  = a.x - m.x, dy  = a.y + m.y;   // 2i*F2
            atomicAdd(&accl[sg * 3 + 0], f1x * dy - f1y * dx);
            atomicAdd(&accl[sg * 3 + 1], f1x * f1x + f1y * f1y);
            atomicAdd(&accl[sg * 3 + 2], dx * dx + dy * dy);
            e = e2; pk = pk2;
        }
    }
    __syncthreads();

    float* prow = partials + (size_t)(row_base + blockIdx.x) * 384;
    for (int i = tid; i < NSEG * 3; i += 512) prow[i] = accl[i];
}

// ---------------------------------------------------------------------------
// Reduce per-block partials -> acc[378]. grid 6 x 64 lanes, coalesced reads.
// ---------------------------------------------------------------------------
__global__ void reduce_partials(const float* __restrict__ partials, int nrows,
                                float* __restrict__ acc) {
    int e = blockIdx.x * 64 + threadIdx.x;
    if (e >= NSEG * 3) return;
    float s0 = 0.f, s1 = 0.f, s2 = 0.f, s3 = 0.f;
    int r = 0;
    for (; r + 4 <= nrows; r += 4) {
        s0 += partials[(size_t)(r + 0) * 384 + e];
        s1 += partials[(size_t)(r + 1) * 384 + e];
        s2 += partials[(size_t)(r + 2) * 384 + e];
        s3 += partials[(size_t)(r + 3) * 384 + e];
    }
    for (; r < nrows; r++) s0 += partials[(size_t)r * 384 + e];
    acc[e] = (s0 + s1) + (s2 + s3);
}

// ---------------------------------------------------------------------------
__global__ void final_kernel(const float* __restrict__ acc, const float* __restrict__ w,
                             float* __restrict__ out, float scale) {
    int lane = threadIdx.x;                       // 64 threads
    float val = 0.f;
    for (int s = lane; s < NSEG; s += 64) {
        float cr = acc[s * 3 + 0];
        float p1 = acc[s * 3 + 1];
        float p2 = acc[s * 3 + 2];
        float den = p1 * p2;
        float curve = den > 0.f ? fabsf(cr) * rsqrtf(den) : 0.f;
        val += curve * w[s + 1];
    }
    if (lane == 0) val += w[0];                   // curve[0] = 1
    #pragma unroll
    for (int off = 32; off > 0; off >>= 1) val += __shfl_down(val, off);
    if (lane == 0) out[0] = scale * val;
}

// ---------------------------------------------------------------------------
extern "C" void kernel_launch(void* const* d_in, const int* in_sizes, int n_in,
                              void* d_out, int out_size, void* d_ws, size_t ws_size,
                              hipStream_t stream)
{
    const float* inp = (const float*)d_in[0];
    const float* tgt = (const float*)d_in[1];
    const float* wts = (const float*)d_in[2];
    const int*   rr  = (const int*)d_in[3];
    const int*   cc  = (const int*)d_in[4];
    const int*   sg  = (const int*)d_in[5];
    int npts   = in_sizes[3];
    int npairs = in_sizes[0] >> 16;               // B*C (65536 px/img)

    char* ws = (char*)d_ws;
    float* acc    = (float*)(ws + 0);             // 378 floats
    int*   counts = (int*)(ws + 2048);            // 128 ints
    int*   starts = (int*)(ws + 2560);            // 129 ints
    int*   cursor = (int*)(ws + 3584);            // 128 ints
    int*   b_pack = (int*)(ws + 4096);
    size_t poff = 4096 + (size_t)npts * 4;
    poff = (poff + 255) & ~(size_t)255;
    float* partials = (float*)(ws + poff);        // (npairs*8) x 384
    size_t goff = poff + (size_t)npairs * 8 * 384 * 4;
    goff = (goff + 255) & ~(size_t)255;
    float2* G = (float2*)(ws + goff);

    size_t per_pair = (size_t)256 * 256 * sizeof(float2);   // 512 KiB
    int maxchunk = (int)((ws_size > goff ? (ws_size - goff) : 0) / per_pair);
    if (maxchunk < 1) maxchunk = 1;
    if (maxchunk > npairs) maxchunk = npairs;

    prep_zero<<<1, 128, 0, stream>>>(counts);
    prep_hist<<<(npts + 255) / 256, 256, 0, stream>>>(rr, cc, npts, counts);
    prep_scan<<<1, 64, 0, stream>>>(counts, starts, cursor);
    prep_scatter<<<(npts + 255) / 256, 256, 0, stream>>>(rr, cc, sg, npts, cursor, b_pack);

    for (int pb = 0; pb < npairs; pb += maxchunk) {
        int cp = npairs - pb < maxchunk ? npairs - pb : maxchunk;
        rowfft_kernel<<<cp * 8, 512, 0, stream>>>(inp, tgt, G, pb);
        colfft_gather_kernel<<<cp * 8, 512, 0, stream>>>(G, starts, b_pack,
                                                         partials, pb * 8);
    }

    reduce_partials<<<6, 64, 0, stream>>>(partials, npairs * 8, acc);
    final_kernel<<<1, 64, 0, stream>>>(acc, wts, (float*)d_out, (float)npairs);
}

// Round 8
// 328.071 us; speedup vs baseline: 1.1825x; 1.1825x over previous
//
#include <hip/hip_runtime.h>
#include <math.h>

#define NSEG 126

__device__ __forceinline__ unsigned bitrev8(unsigned v) { return __brev(v) >> 24; }

// ---------------------------------------------------------------------------
// K interleaved register-resident 256-point DIF FFTs per wave (proven core).
// FFT k: element e = i*64 + lane in x[k][i]. On exit x[k][i] = X[bitrev8(e)].
// ---------------------------------------------------------------------------
template <int K>
__device__ __forceinline__ void fftK(float2 x[][4], int lane) {
    const float PI = 3.14159265358979323846f;
    {   // stage M=256
        float s, c;
        __sincosf(-PI * (float)lane * (1.0f / 128.0f), &s, &c);
        #pragma unroll
        for (int k = 0; k < K; k++) {
            float2 u, t, d;
            u = x[k][0]; t = x[k][2];
            x[k][0] = make_float2(u.x + t.x, u.y + t.y);
            d = make_float2(u.x - t.x, u.y - t.y);
            x[k][2] = make_float2(d.x * c - d.y * s, d.x * s + d.y * c);
            u = x[k][1]; t = x[k][3];
            x[k][1] = make_float2(u.x + t.x, u.y + t.y);
            d = make_float2(u.x - t.x, u.y - t.y);
            x[k][3] = make_float2(d.x * s + d.y * c, -d.x * c + d.y * s); // * (s,-c)
        }
    }
    {   // stage M=128
        float s, c;
        __sincosf(-PI * (float)lane * (1.0f / 64.0f), &s, &c);
        #pragma unroll
        for (int k = 0; k < K; k++) {
            float2 u, t, d;
            u = x[k][0]; t = x[k][1];
            x[k][0] = make_float2(u.x + t.x, u.y + t.y);
            d = make_float2(u.x - t.x, u.y - t.y);
            x[k][1] = make_float2(d.x * c - d.y * s, d.x * s + d.y * c);
            u = x[k][2]; t = x[k][3];
            x[k][2] = make_float2(u.x + t.x, u.y + t.y);
            d = make_float2(u.x - t.x, u.y - t.y);
            x[k][3] = make_float2(d.x * c - d.y * s, d.x * s + d.y * c);
        }
    }
    #pragma unroll
    for (int hbit = 5; hbit >= 0; hbit--) {   // stages M=64..2, cross-lane
        int h = 1 << hbit;
        int j = lane & (h - 1);
        float s, c;
        __sincosf(-PI * (float)j / (float)h, &s, &c);
        bool up = (lane & h) != 0;
        #pragma unroll
        for (int k = 0; k < K; k++) {
            #pragma unroll
            for (int i = 0; i < 4; i++) {
                float px = __shfl_xor(x[k][i].x, h);
                float py = __shfl_xor(x[k][i].y, h);
                if (up) {
                    float dx = px - x[k][i].x, dy = py - x[k][i].y;
                    x[k][i] = make_float2(dx * c - dy * s, dx * s + dy * c);
                } else {
                    x[k][i] = make_float2(x[k][i].x + px, x[k][i].y + py);
                }
            }
        }
    }
}

// ---------------------------------------------------------------------------
// prep: keep half-plane (c>128 || (c==128 && r>128)); bucket j = 255-c;
// pack (bitrev(r), bitrev(256-r), seg).
// ---------------------------------------------------------------------------
__global__ void prep_zero(float* acc, int* counts) {
    int i = threadIdx.x;                          // 512 threads
    if (i < NSEG * 3) acc[i] = 0.f;
    if (i < 128) counts[i] = 0;
}

__device__ __forceinline__ bool keep_point(int r, int c) {
    return (c > 128) || (c == 128 && r > 128);
}

__global__ void prep_hist(const int* __restrict__ rr, const int* __restrict__ cc,
                          int n, int* counts) {
    int i = blockIdx.x * 256 + threadIdx.x;
    if (i < n) {
        int c = cc[i], r = rr[i];
        if (keep_point(r, c)) atomicAdd(&counts[255 - c], 1);
    }
}

__global__ void prep_scan(const int* __restrict__ counts, int* starts, int* cursor) {
    int lane = threadIdx.x;                      // 64 threads, 2 counts each
    int2 c = reinterpret_cast<const int2*>(counts)[lane];
    int lsum = c.x + c.y;
    int pre = lsum;
    #pragma unroll
    for (int off = 1; off < 64; off <<= 1) {
        int v = __shfl_up(pre, off);
        if (lane >= off) pre += v;
    }
    int excl = pre - lsum;
    int2 outv = make_int2(excl, excl + c.x);
    reinterpret_cast<int2*>(starts)[lane] = outv;
    reinterpret_cast<int2*>(cursor)[lane] = outv;
    if (lane == 63) starts[128] = excl + c.x + c.y;
}

__global__ void prep_scatter(const int* __restrict__ rr, const int* __restrict__ cc,
                             const int* __restrict__ seg, int n, int* cursor,
                             int* b_pack) {
    int i = blockIdx.x * 256 + threadIdx.x;
    if (i < n) {
        int c = cc[i], r = rr[i];
        if (keep_point(r, c)) {
            int j = 255 - c;
            int pos = atomicAdd(&cursor[j], 1);
            int pr = (int)bitrev8((unsigned)r);
            int pm = (int)bitrev8((unsigned)(256 - r) & 255);
            b_pack[pos] = pr | (pm << 8) | (seg[i] << 16);
        }
    }
}

// ---------------------------------------------------------------------------
// Row-pass: packed z = in + i*tgt; 2 rows/wave, 8 waves = 16 rows/block.
// blockIdx = rowgrp*cp + plocal  (cp % 8 == 0 -> pair pinned to XCD plocal%8).
// Output Gt: physical row q holds X[bitrev8(q)], x-major. Inputs nontemporal.
// ---------------------------------------------------------------------------
__global__ __launch_bounds__(512) void rowfft_kernel(
    const float* __restrict__ inp, const float* __restrict__ tgt,
    float2* __restrict__ G, int pair_base, int cp)
{
    __shared__ float2 T[256 * 17];
    int bid    = blockIdx.x;
    int plocal = bid % cp;
    int rowgrp = bid / cp;                        // [0,16)
    int wv     = threadIdx.x >> 6;
    int lane   = threadIdx.x & 63;
    size_t base = (((size_t)(pair_base + plocal)) << 16)
                + ((size_t)((rowgrp << 4) + (wv << 1)) << 8);
    const float* s1 = inp + base;
    const float* s2 = tgt + base;

    float2 x[2][4];
    #pragma unroll
    for (int k = 0; k < 2; k++)
        #pragma unroll
        for (int i = 0; i < 4; i++) {
            int e = (k << 8) + i * 64 + lane;
            x[k][i] = make_float2(__builtin_nontemporal_load(&s1[e]),
                                  __builtin_nontemporal_load(&s2[e]));
        }
    fftK<2>(x, lane);

    #pragma unroll
    for (int k = 0; k < 2; k++)
        #pragma unroll
        for (int i = 0; i < 4; i++)
            T[(i * 64 + lane) * 17 + (wv << 1) + k] = x[k][i];
    __syncthreads();

    float2* dst = G + (((size_t)plocal) << 16) + (rowgrp << 4);
    int xl = threadIdx.x & 15;
    int qb = threadIdx.x >> 4;                    // 0..31
    #pragma unroll
    for (int ii = 0; ii < 8; ii++) {
        int q = qb + (ii << 5);
        dst[q * 256 + xl] = T[q * 17 + xl];
    }
}

// ---------------------------------------------------------------------------
// Column-pass + gather. 256 thr = 4 waves; block = 8 buckets; 16 blocks/pair.
// blockIdx = b*cp + plocal  (same XCD as the rowfft that wrote this pair ->
// G reads hit the local L2). Two-phase per-wave LDS slot, ~18 KiB -> 8 blk/CU.
// ---------------------------------------------------------------------------
__global__ __launch_bounds__(256) void colfft_gather_kernel(
    const float2* __restrict__ G, const int* __restrict__ starts,
    const int* __restrict__ b_pack, float* __restrict__ acc, int cp)
{
    __shared__ float2 Fb[4][2][256];             // 16 KiB (per-wave bucket slot)
    __shared__ float accl[NSEG * 3];
    int tid    = threadIdx.x;
    int wv     = tid >> 6;
    int lane   = tid & 63;
    int bid    = blockIdx.x;
    int plocal = bid % cp;
    int b      = bid / cp;                       // [0,16)
    int jbase  = (b << 3) + (wv << 1);           // wave's buckets: jbase, jbase+1

    for (int i = tid; i < NSEG * 3; i += 256) accl[i] = 0.f;
    __syncthreads();

    const float2* Gp = G + (((size_t)plocal) << 16);
    int cols[4];
    cols[0] = jbase + 1;   cols[1] = 255 - jbase;        // bucket jbase   (lo, hi)
    cols[2] = jbase + 2;   cols[3] = 254 - jbase;        // bucket jbase+1 (lo, hi)

    float2 x[4][4];
    #pragma unroll
    for (int k = 0; k < 4; k++) {
        int q = (int)bitrev8((unsigned)cols[k]);
        const float2* col = Gp + ((size_t)q << 8);
        #pragma unroll
        for (int i = 0; i < 4; i++) x[k][i] = col[i * 64 + lane];
    }

    fftK<4>(x, lane);

    float2* F_lo = &Fb[wv][0][0];
    float2* F_hi = &Fb[wv][1][0];
    #pragma unroll
    for (int kb = 0; kb < 2; kb++) {
        #pragma unroll
        for (int i = 0; i < 4; i++) {
            F_lo[i * 64 + lane] = x[2 * kb + 0][i];
            F_hi[i * 64 + lane] = x[2 * kb + 1][i];
        }
        int j = jbase + kb;
        int s0 = starts[j], s1 = starts[j + 1];
        int e  = s0 + lane;
        int pk = (e < s1) ? b_pack[e] : 0;       // pipelined global load
        while (e < s1) {
            int e2  = e + 64;
            int pk2 = (e2 < s1) ? b_pack[e2] : 0;
            float2 a = F_hi[pk & 255];            // Fp(r, c)
            float2 m = F_lo[(pk >> 8) & 255];     // Fp(-r, -c)
            int sg = pk >> 16;
            float f1x = a.x + m.x, f1y = a.y - m.y;   // 2*F1
            float dx  = a.x - m.x, dy  = a.y + m.y;   // 2i*F2
            atomicAdd(&accl[sg * 3 + 0], f1x * dy - f1y * dx);
            atomicAdd(&accl[sg * 3 + 1], f1x * f1x + f1y * f1y);
            atomicAdd(&accl[sg * 3 + 2], dx * dx + dy * dy);
            e = e2; pk = pk2;
        }
    }
    __syncthreads();

    for (int i = tid; i < NSEG * 3; i += 256) {
        float v = accl[i];
        if (v != 0.f) atomicAdd(&acc[i], v);
    }
}

// ---------------------------------------------------------------------------
__global__ void final_kernel(const float* __restrict__ acc, const float* __restrict__ w,
                             float* __restrict__ out, float scale) {
    int lane = threadIdx.x;                       // 64 threads
    float val = 0.f;
    for (int s = lane; s < NSEG; s += 64) {
        float cr = acc[s * 3 + 0];
        float p1 = acc[s * 3 + 1];
        float p2 = acc[s * 3 + 2];
        float den = p1 * p2;
        float curve = den > 0.f ? fabsf(cr) * rsqrtf(den) : 0.f;
        val += curve * w[s + 1];
    }
    if (lane == 0) val += w[0];                   // curve[0] = 1
    #pragma unroll
    for (int off = 32; off > 0; off >>= 1) val += __shfl_down(val, off);
    if (lane == 0) out[0] = scale * val;
}

// ---------------------------------------------------------------------------
extern "C" void kernel_launch(void* const* d_in, const int* in_sizes, int n_in,
                              void* d_out, int out_size, void* d_ws, size_t ws_size,
                              hipStream_t stream)
{
    const float* inp = (const float*)d_in[0];
    const float* tgt = (const float*)d_in[1];
    const float* wts = (const float*)d_in[2];
    const int*   rr  = (const int*)d_in[3];
    const int*   cc  = (const int*)d_in[4];
    const int*   sg  = (const int*)d_in[5];
    int npts   = in_sizes[3];
    int npairs = in_sizes[0] >> 16;               // B*C (65536 px/img)

    char* ws = (char*)d_ws;
    float* acc    = (float*)(ws + 0);             // 378 floats
    int*   counts = (int*)(ws + 2048);            // 128 ints
    int*   starts = (int*)(ws + 2560);            // 129 ints
    int*   cursor = (int*)(ws + 3584);            // 128 ints
    int*   b_pack = (int*)(ws + 4096);
    size_t goff = 4096 + (size_t)npts * 4;
    goff = (goff + 255) & ~(size_t)255;
    float2* G = (float2*)(ws + goff);

    size_t per_pair = (size_t)256 * 256 * sizeof(float2);   // 512 KiB
    int maxchunk = (int)((ws_size > goff ? (ws_size - goff) : 0) / per_pair);
    if (maxchunk < 1) maxchunk = 1;
    // chunk: 32 pairs -> 2 MiB of G per XCD (L2-resident) with blockIdx%8 pinning
    int PC = 32;
    if (PC > maxchunk) PC = (maxchunk >= 8) ? (maxchunk & ~7) : maxchunk;
    if (PC > npairs) PC = npairs;

    prep_zero<<<1, 512, 0, stream>>>(acc, counts);
    prep_hist<<<(npts + 255) / 256, 256, 0, stream>>>(rr, cc, npts, counts);
    prep_scan<<<1, 64, 0, stream>>>(counts, starts, cursor);
    prep_scatter<<<(npts + 255) / 256, 256, 0, stream>>>(rr, cc, sg, npts, cursor, b_pack);

    for (int pb = 0; pb < npairs; pb += PC) {
        int cp = npairs - pb < PC ? npairs - pb : PC;
        rowfft_kernel<<<cp * 16, 512, 0, stream>>>(inp, tgt, G, pb, cp);
        colfft_gather_kernel<<<cp * 16, 256, 0, stream>>>(G, starts, b_pack, acc, cp);
    }

    final_kernel<<<1, 64, 0, stream>>>(acc, wts, (float*)d_out, (float)npairs);
}

// Round 9
// 236.389 us; speedup vs baseline: 1.6411x; 1.3878x over previous
//
#include <hip/hip_runtime.h>
#include <hip/hip_fp16.h>
#include <math.h>

#define NSEG 126

__device__ __forceinline__ unsigned bitrev8(unsigned v) { return __brev(v) >> 24; }

// ---------------------------------------------------------------------------
// K interleaved register-resident 256-point DIF FFTs per wave (proven core).
// FFT k: element e = i*64 + lane in x[k][i]. On exit x[k][i] = X[bitrev8(e)].
// ---------------------------------------------------------------------------
template <int K>
__device__ __forceinline__ void fftK(float2 x[][4], int lane) {
    const float PI = 3.14159265358979323846f;
    {   // stage M=256
        float s, c;
        __sincosf(-PI * (float)lane * (1.0f / 128.0f), &s, &c);
        #pragma unroll
        for (int k = 0; k < K; k++) {
            float2 u, t, d;
            u = x[k][0]; t = x[k][2];
            x[k][0] = make_float2(u.x + t.x, u.y + t.y);
            d = make_float2(u.x - t.x, u.y - t.y);
            x[k][2] = make_float2(d.x * c - d.y * s, d.x * s + d.y * c);
            u = x[k][1]; t = x[k][3];
            x[k][1] = make_float2(u.x + t.x, u.y + t.y);
            d = make_float2(u.x - t.x, u.y - t.y);
            x[k][3] = make_float2(d.x * s + d.y * c, -d.x * c + d.y * s); // * (s,-c)
        }
    }
    {   // stage M=128
        float s, c;
        __sincosf(-PI * (float)lane * (1.0f / 64.0f), &s, &c);
        #pragma unroll
        for (int k = 0; k < K; k++) {
            float2 u, t, d;
            u = x[k][0]; t = x[k][1];
            x[k][0] = make_float2(u.x + t.x, u.y + t.y);
            d = make_float2(u.x - t.x, u.y - t.y);
            x[k][1] = make_float2(d.x * c - d.y * s, d.x * s + d.y * c);
            u = x[k][2]; t = x[k][3];
            x[k][2] = make_float2(u.x + t.x, u.y + t.y);
            d = make_float2(u.x - t.x, u.y - t.y);
            x[k][3] = make_float2(d.x * c - d.y * s, d.x * s + d.y * c);
        }
    }
    #pragma unroll
    for (int hbit = 5; hbit >= 0; hbit--) {   // stages M=64..2, cross-lane
        int h = 1 << hbit;
        int j = lane & (h - 1);
        float s, c;
        __sincosf(-PI * (float)j / (float)h, &s, &c);
        bool up = (lane & h) != 0;
        #pragma unroll
        for (int k = 0; k < K; k++) {
            #pragma unroll
            for (int i = 0; i < 4; i++) {
                float px = __shfl_xor(x[k][i].x, h);
                float py = __shfl_xor(x[k][i].y, h);
                if (up) {
                    float dx = px - x[k][i].x, dy = py - x[k][i].y;
                    x[k][i] = make_float2(dx * c - dy * s, dx * s + dy * c);
                } else {
                    x[k][i] = make_float2(x[k][i].x + px, x[k][i].y + py);
                }
            }
        }
    }
}

// ---------------------------------------------------------------------------
// Fused prep: single block, LDS histogram + scan + LDS cursors (no global
// atomic contention). keep half-plane (c>128 || (c==128 && r>128));
// bucket j = 255-c; pack (bitrev(r), bitrev(256-r), seg). Also zeros acc.
// ---------------------------------------------------------------------------
__global__ __launch_bounds__(1024) void prep_all(
    const int* __restrict__ rr, const int* __restrict__ cc,
    const int* __restrict__ seg, int n,
    int* __restrict__ starts, int* __restrict__ b_pack, float* __restrict__ acc)
{
    __shared__ int cnt[128];
    __shared__ int cur[128];
    int tid = threadIdx.x;
    if (tid < NSEG * 3) acc[tid] = 0.f;
    if (tid < 128) cnt[tid] = 0;
    __syncthreads();
    for (int i = tid; i < n; i += 1024) {
        int c = cc[i], r = rr[i];
        if ((c > 128) || (c == 128 && r > 128)) atomicAdd(&cnt[255 - c], 1);
    }
    __syncthreads();
    if (tid < 64) {
        int2 c2 = reinterpret_cast<const int2*>(cnt)[tid];
        int lsum = c2.x + c2.y;
        int pre = lsum;
        #pragma unroll
        for (int off = 1; off < 64; off <<= 1) {
            int v = __shfl_up(pre, off);
            if (tid >= off) pre += v;
        }
        int excl = pre - lsum;
        int2 outv = make_int2(excl, excl + c2.x);
        reinterpret_cast<int2*>(cur)[tid] = outv;
        reinterpret_cast<int2*>(starts)[tid] = outv;
        if (tid == 63) starts[128] = excl + c2.x + c2.y;
    }
    __syncthreads();
    for (int i = tid; i < n; i += 1024) {
        int c = cc[i], r = rr[i];
        if ((c > 128) || (c == 128 && r > 128)) {
            int j = 255 - c;
            int pos = atomicAdd(&cur[j], 1);
            int pr = (int)bitrev8((unsigned)r);
            int pm = (int)bitrev8((unsigned)(256 - r) & 255);
            b_pack[pos] = pr | (pm << 8) | (seg[i] << 16);
        }
    }
}

// ---------------------------------------------------------------------------
// Row-pass: packed z = in + i*tgt; 2 rows/wave, 8 waves = 16 rows/block.
// Output Gt fp16: physical row q holds X[bitrev8(q)] as half2, x-major.
// ---------------------------------------------------------------------------
__global__ __launch_bounds__(512) void rowfft_kernel(
    const float* __restrict__ inp, const float* __restrict__ tgt,
    __half2* __restrict__ G, int pair_base)
{
    __shared__ float2 T[256 * 17];
    int bid    = blockIdx.x;
    int plocal = bid >> 4;
    int rowgrp = bid & 15;
    int wv     = threadIdx.x >> 6;
    int lane   = threadIdx.x & 63;
    size_t base = (((size_t)(pair_base + plocal)) << 16)
                + ((size_t)((rowgrp << 4) + (wv << 1)) << 8);
    const float* s1 = inp + base;
    const float* s2 = tgt + base;

    float2 x[2][4];
    #pragma unroll
    for (int k = 0; k < 2; k++)
        #pragma unroll
        for (int i = 0; i < 4; i++) {
            int e = (k << 8) + i * 64 + lane;
            x[k][i] = make_float2(s1[e], s2[e]);
        }
    fftK<2>(x, lane);

    #pragma unroll
    for (int k = 0; k < 2; k++)
        #pragma unroll
        for (int i = 0; i < 4; i++)
            T[(i * 64 + lane) * 17 + (wv << 1) + k] = x[k][i];
    __syncthreads();

    __half2* dst = G + (((size_t)plocal) << 16) + (rowgrp << 4);
    int xl = threadIdx.x & 15;
    int qb = threadIdx.x >> 4;                    // 0..31
    #pragma unroll
    for (int ii = 0; ii < 8; ii++) {
        int q = qb + (ii << 5);
        float2 v = T[q * 17 + xl];
        dst[q * 256 + xl] = __float22half2_rn(v);
    }
}

// ---------------------------------------------------------------------------
// Column-pass + gather (R5-proven structure, fp16 G loads). 256 thr = 4
// waves; wave owns 2 buckets (4 columns); two-phase per-wave LDS slot.
// ---------------------------------------------------------------------------
__global__ __launch_bounds__(256) void colfft_gather_kernel(
    const __half2* __restrict__ G, const int* __restrict__ starts,
    const int* __restrict__ b_pack, float* __restrict__ acc)
{
    __shared__ float2 Fb[4][2][256];             // 16 KiB (per-wave bucket slot)
    __shared__ float accl[NSEG * 3];
    int tid    = threadIdx.x;
    int wv     = tid >> 6;
    int lane   = tid & 63;
    int plocal = blockIdx.x >> 4;
    int b      = blockIdx.x & 15;
    int jbase  = (b << 3) + (wv << 1);           // wave's buckets: jbase, jbase+1

    for (int i = tid; i < NSEG * 3; i += 256) accl[i] = 0.f;
    __syncthreads();

    const __half2* Gp = G + (((size_t)plocal) << 16);
    int cols[4];
    cols[0] = jbase + 1;   cols[1] = 255 - jbase;        // bucket jbase   (lo, hi)
    cols[2] = jbase + 2;   cols[3] = 254 - jbase;        // bucket jbase+1 (lo, hi)

    __half2 h[4][4];
    #pragma unroll
    for (int k = 0; k < 4; k++) {
        int q = (int)bitrev8((unsigned)cols[k]);
        const __half2* col = Gp + ((size_t)q << 8);
        #pragma unroll
        for (int i = 0; i < 4; i++) h[k][i] = col[i * 64 + lane];
    }
    float2 x[4][4];
    #pragma unroll
    for (int k = 0; k < 4; k++)
        #pragma unroll
        for (int i = 0; i < 4; i++)
            x[k][i] = __half22float2(h[k][i]);

    fftK<4>(x, lane);

    float2* F_lo = &Fb[wv][0][0];
    float2* F_hi = &Fb[wv][1][0];
    #pragma unroll
    for (int kb = 0; kb < 2; kb++) {
        #pragma unroll
        for (int i = 0; i < 4; i++) {
            F_lo[i * 64 + lane] = x[2 * kb + 0][i];
            F_hi[i * 64 + lane] = x[2 * kb + 1][i];
        }
        int j = jbase + kb;
        int s0 = starts[j], s1 = starts[j + 1];
        int e  = s0 + lane;
        int pk = (e < s1) ? b_pack[e] : 0;       // pipelined global load
        while (e < s1) {
            int e2  = e + 64;
            int pk2 = (e2 < s1) ? b_pack[e2] : 0;
            float2 a = F_hi[pk & 255];            // Fp(r, c)
            float2 m = F_lo[(pk >> 8) & 255];     // Fp(-r, -c)
            int sg = pk >> 16;
            float f1x = a.x + m.x, f1y = a.y - m.y;   // 2*F1
            float dx  = a.x - m.x, dy  = a.y + m.y;   // 2i*F2
            atomicAdd(&accl[sg * 3 + 0], f1x * dy - f1y * dx);
            atomicAdd(&accl[sg * 3 + 1], f1x * f1x + f1y * f1y);
            atomicAdd(&accl[sg * 3 + 2], dx * dx + dy * dy);
            e = e2; pk = pk2;
        }
    }
    __syncthreads();

    for (int i = tid; i < NSEG * 3; i += 256) {
        float v = accl[i];
        if (v != 0.f) atomicAdd(&acc[i], v);
    }
}

// ---------------------------------------------------------------------------
__global__ void final_kernel(const float* __restrict__ acc, const float* __restrict__ w,
                             float* __restrict__ out, float scale) {
    int lane = threadIdx.x;                       // 64 threads
    float val = 0.f;
    for (int s = lane; s < NSEG; s += 64) {
        float cr = acc[s * 3 + 0];
        float p1 = acc[s * 3 + 1];
        float p2 = acc[s * 3 + 2];
        float den = p1 * p2;
        float curve = den > 0.f ? fabsf(cr) * rsqrtf(den) : 0.f;
        val += curve * w[s + 1];
    }
    if (lane == 0) val += w[0];                   // curve[0] = 1
    #pragma unroll
    for (int off = 32; off > 0; off >>= 1) val += __shfl_down(val, off);
    if (lane == 0) out[0] = scale * val;
}

// ---------------------------------------------------------------------------
extern "C" void kernel_launch(void* const* d_in, const int* in_sizes, int n_in,
                              void* d_out, int out_size, void* d_ws, size_t ws_size,
                              hipStream_t stream)
{
    const float* inp = (const float*)d_in[0];
    const float* tgt = (const float*)d_in[1];
    const float* wts = (const float*)d_in[2];
    const int*   rr  = (const int*)d_in[3];
    const int*   cc  = (const int*)d_in[4];
    const int*   sg  = (const int*)d_in[5];
    int npts   = in_sizes[3];
    int npairs = in_sizes[0] >> 16;               // B*C (65536 px/img)

    char* ws = (char*)d_ws;
    float* acc    = (float*)(ws + 0);             // 378 floats
    int*   starts = (int*)(ws + 2048);            // 129 ints
    int*   b_pack = (int*)(ws + 4096);
    size_t goff = 4096 + (size_t)npts * 4;
    goff = (goff + 255) & ~(size_t)255;
    __half2* G = (__half2*)(ws + goff);

    size_t per_pair = (size_t)256 * 256 * sizeof(__half2);  // 256 KiB
    int maxchunk = (int)((ws_size > goff ? (ws_size - goff) : 0) / per_pair);
    if (maxchunk < 1) maxchunk = 1;
    if (maxchunk > npairs) maxchunk = npairs;

    prep_all<<<1, 1024, 0, stream>>>(rr, cc, sg, npts, starts, b_pack, acc);

    for (int pb = 0; pb < npairs; pb += maxchunk) {
        int cp = npairs - pb < maxchunk ? npairs - pb : maxchunk;
        rowfft_kernel<<<cp * 16, 512, 0, stream>>>(inp, tgt, G, pb);
        colfft_gather_kernel<<<cp * 16, 256, 0, stream>>>(G, starts, b_pack, acc);
    }

    final_kernel<<<1, 64, 0, stream>>>(acc, wts, (float*)d_out, (float)npairs);
}